// Round 1
// baseline (524.273 us; speedup 1.0000x reference)
//
#include <hip/hip_runtime.h>
#include <hip/hip_bf16.h>

#define GN   8192
#define KDIM 256
#define ODIM 64
#define JC   256           // j-chunk per block iteration
#define RPB  32            // rows per block (kernel 2)
#define TSTR (JC + 8)      // 264 elements: 528B row stride, even bank spread, 16B aligned

typedef __attribute__((ext_vector_type(8))) short bf16x8;
typedef __attribute__((ext_vector_type(4))) float f32x4;

__device__ __forceinline__ short f2bf(float x) {
  __hip_bfloat16 b = __float2bfloat16(x);
  return *reinterpret_cast<short*>(&b);
}

// Kernel 1: h = input @ W  (fp32 compute), emit hT (bf16, [ODIM][GN]),
// f1/f2 fp32 partials per column-half. Grid: 256 blocks = 128 row-groups x 2 col-halves.
__global__ __launch_bounds__(256) void gat_k1(
    const float* __restrict__ input, const float* __restrict__ W,
    const float* __restrict__ a, __hip_bfloat16* __restrict__ hT,
    float* __restrict__ f1p, float* __restrict__ f2p)
{
  __shared__ float inT[256 * 65];   // [k][row], pad 65 -> conflict-free reads
  __shared__ float p1[4][64];
  __shared__ float p2[4][64];
  const int tid = threadIdx.x;
  const int rg = blockIdx.x >> 1;   // row group
  const int ch = blockIdx.x & 1;    // column half
  const int i0 = rg * 64;
  const int c0 = ch * 32;

  // stage input tile [64 rows][256 k] transposed into LDS
  for (int idx = tid; idx < 64 * 64; idx += 256) {
    int r = idx >> 6, k4 = idx & 63;
    float4 v = *(const float4*)(input + (long)(i0 + r) * KDIM + k4 * 4);
    inT[(k4 * 4 + 0) * 65 + r] = v.x;
    inT[(k4 * 4 + 1) * 65 + r] = v.y;
    inT[(k4 * 4 + 2) * 65 + r] = v.z;
    inT[(k4 * 4 + 3) * 65 + r] = v.w;
  }
  __syncthreads();

  const int lr = tid & 63;                                   // row within tile
  const int cg = __builtin_amdgcn_readfirstlane(tid >> 6);   // wave-uniform col group
  const float* Wp = W + c0 + cg * 8;                         // uniform -> s_load path
  float acc[8];
#pragma unroll
  for (int c = 0; c < 8; ++c) acc[c] = 0.f;
#pragma unroll 4
  for (int k = 0; k < 256; ++k) {
    float inv = inT[k * 65 + lr];
#pragma unroll
    for (int c = 0; c < 8; ++c) acc[c] += inv * Wp[k * 64 + c];
  }
  // hT[col][row] bf16
#pragma unroll
  for (int c = 0; c < 8; ++c)
    hT[(long)(c0 + cg * 8 + c) * GN + i0 + lr] = __float2bfloat16(acc[c]);

  // f1/f2 partial over this column half
  float s1 = 0.f, s2 = 0.f;
#pragma unroll
  for (int c = 0; c < 8; ++c) {
    s1 += acc[c] * a[c0 + cg * 8 + c];
    s2 += acc[c] * a[ODIM + c0 + cg * 8 + c];
  }
  p1[cg][lr] = s1; p2[cg][lr] = s2;
  __syncthreads();
  if (tid < 64) {
    f1p[ch * GN + i0 + tid] = p1[0][tid] + p1[1][tid] + p1[2][tid] + p1[3][tid];
    f2p[ch * GN + i0 + tid] = p2[0][tid] + p2[1][tid] + p2[2][tid] + p2[3][tid];
  }
}

// Kernel 2: fused mask + softmax (no-max, ratio-invariant) + alpha@h via bf16 MFMA.
// 256 blocks x 32 rows; per chunk: prefetch regs -> w-gen into LDS -> MFMA.
__global__ __launch_bounds__(256, 1) void gat_k2(
    const int* __restrict__ adj, const __hip_bfloat16* __restrict__ hT,
    const float* __restrict__ f1p, const float* __restrict__ f2p,
    float* __restrict__ out)
{
  __shared__ short w_tile[RPB * TSTR];        // 16.9 KB
  __shared__ short h_tile[ODIM * TSTR];       // 33.8 KB
  __shared__ float f1c[RPB];
  __shared__ float sbuf[2][RPB];
  __shared__ float pbuf[2][RPB][ODIM];        // 16 KB

  const int tid = threadIdx.x;
  const int lane = tid & 63;
  const int wv = tid >> 6;
  const int rowhalf = wv & 1;                 // which 16-row half of the 32
  const int jhalf = wv >> 1;                  // which 128-j half of the chunk
  const int tn = lane & 15;
  const int quad = lane >> 4;
  const int i0 = blockIdx.x * RPB;

  // the three scalar e-outputs (rows/cols 1..3; f1/f2 complete after k1)
  if (blockIdx.x == 0 && tid == 0) {
    float f11 = f1p[1] + f1p[GN + 1];
    float f13 = f1p[3] + f1p[GN + 3];
    float f22 = f2p[2] + f2p[GN + 2];
    float f23 = f2p[3] + f2p[GN + 3];
    float e12 = f11 + f22, e13 = f11 + f23, e32 = f13 + f22;
    out[GN * ODIM + 0] = fmaxf(e12, 0.01f * e12);
    out[GN * ODIM + 1] = fmaxf(e13, 0.01f * e13);
    out[GN * ODIM + 2] = fmaxf(e32, 0.01f * e32);
  }

  if (tid < RPB) f1c[tid] = f1p[i0 + tid] + f1p[GN + i0 + tid];

  const int tj = (tid & 63) * 4;    // adj/w j-offset within chunk
  const int tr = tid >> 6;          // adj base row (rows tr, tr+4, ..., tr+28)
  const int hr = tid >> 5;          // h base row (rows hr, hr+8, ..., hr+56)
  const int hj = (tid & 31) * 8;    // h j-offset (bf16 elements)

  int4 areg[8];
  int4 hreg[8];
  float4 f2v;

  {  // prefetch chunk 0
#pragma unroll
    for (int it = 0; it < 8; ++it)
      areg[it] = *(const int4*)(adj + (long)(i0 + it * 4 + tr) * GN + tj);
#pragma unroll
    for (int it = 0; it < 8; ++it)
      hreg[it] = *(const int4*)(hT + (long)(it * 8 + hr) * GN + hj);
    float4 fa = *(const float4*)(f2p + tj);
    float4 fb = *(const float4*)(f2p + GN + tj);
    f2v.x = fa.x + fb.x; f2v.y = fa.y + fb.y; f2v.z = fa.z + fb.z; f2v.w = fa.w + fb.w;
  }

  f32x4 acc[4];
  f32x4 accS;
#pragma unroll
  for (int nf = 0; nf < 4; ++nf) acc[nf] = (f32x4){0.f, 0.f, 0.f, 0.f};
  accS = (f32x4){0.f, 0.f, 0.f, 0.f};

  bf16x8 ones;  // B-frag: ones in column n==0 only -> denominator via MFMA
  {
    short ov = (tn == 0) ? (short)0x3F80 : (short)0;
#pragma unroll
    for (int i = 0; i < 8; ++i) ones[i] = ov;
  }

  for (int c = 0; c < GN / JC; ++c) {
    __syncthreads();  // tiles free (previous MFMA done)
    // w-gen: bf16 w = [adj>0] * exp(lrelu(f1+f2)) into LDS
#pragma unroll
    for (int it = 0; it < 8; ++it) {
      int r = it * 4 + tr;
      float fe = f1c[r];
      float e0 = fe + f2v.x, e1 = fe + f2v.y, e2 = fe + f2v.z, e3 = fe + f2v.w;
      float w0 = (areg[it].x > 0) ? exp2f(fmaxf(e0, 0.01f * e0) * 1.44269504f) : 0.f;
      float w1 = (areg[it].y > 0) ? exp2f(fmaxf(e1, 0.01f * e1) * 1.44269504f) : 0.f;
      float w2 = (areg[it].z > 0) ? exp2f(fmaxf(e2, 0.01f * e2) * 1.44269504f) : 0.f;
      float w3 = (areg[it].w > 0) ? exp2f(fmaxf(e3, 0.01f * e3) * 1.44269504f) : 0.f;
      short4 wv4;
      wv4.x = f2bf(w0); wv4.y = f2bf(w1); wv4.z = f2bf(w2); wv4.w = f2bf(w3);
      *(short4*)&w_tile[r * TSTR + tj] = wv4;
    }
#pragma unroll
    for (int it = 0; it < 8; ++it)
      *(int4*)&h_tile[(it * 8 + hr) * TSTR + hj] = hreg[it];

    if (c + 1 < GN / JC) {  // prefetch next chunk (overlaps barrier + MFMA)
      const int jc = (c + 1) * JC;
#pragma unroll
      for (int it = 0; it < 8; ++it)
        areg[it] = *(const int4*)(adj + (long)(i0 + it * 4 + tr) * GN + jc + tj);
#pragma unroll
      for (int it = 0; it < 8; ++it)
        hreg[it] = *(const int4*)(hT + (long)(it * 8 + hr) * GN + jc + hj);
      float4 fa = *(const float4*)(f2p + jc + tj);
      float4 fb = *(const float4*)(f2p + GN + jc + tj);
      f2v.x = fa.x + fb.x; f2v.y = fa.y + fb.y; f2v.z = fa.z + fb.z; f2v.w = fa.w + fb.w;
    }
    __syncthreads();  // tiles ready

    // MFMA: A = w[16 rows x 32 j], B = h[32 j x 16 cols] (+ ones col for sum)
#pragma unroll
    for (int ks = 0; ks < 4; ++ks) {
      const int koff = jhalf * 128 + ks * 32 + quad * 8;
      bf16x8 afr = *(const bf16x8*)&w_tile[(rowhalf * 16 + tn) * TSTR + koff];
#pragma unroll
      for (int nf = 0; nf < 4; ++nf) {
        bf16x8 bfr = *(const bf16x8*)&h_tile[(nf * 16 + tn) * TSTR + koff];
        acc[nf] = __builtin_amdgcn_mfma_f32_16x16x32_bf16(afr, bfr, acc[nf], 0, 0, 0);
      }
      accS = __builtin_amdgcn_mfma_f32_16x16x32_bf16(afr, ones, accS, 0, 0, 0);
    }
  }

  // epilogue: combine jhalf partials, divide by row sums, store
  __syncthreads();
  if (tn == 0) {
#pragma unroll
    for (int rgi = 0; rgi < 4; ++rgi)
      sbuf[jhalf][rowhalf * 16 + quad * 4 + rgi] = accS[rgi];
  }
#pragma unroll
  for (int nf = 0; nf < 4; ++nf)
#pragma unroll
    for (int rgi = 0; rgi < 4; ++rgi)
      pbuf[jhalf][rowhalf * 16 + quad * 4 + rgi][nf * 16 + tn] = acc[nf][rgi];
  __syncthreads();
  for (int t = tid; t < RPB * ODIM; t += 256) {
    int r = t >> 6, cc = t & 63;
    float s = sbuf[0][r] + sbuf[1][r];
    out[(long)(i0 + r) * ODIM + cc] = (pbuf[0][r][cc] + pbuf[1][r][cc]) / s;
  }
}

extern "C" void kernel_launch(void* const* d_in, const int* in_sizes, int n_in,
                              void* d_out, int out_size, void* d_ws, size_t ws_size,
                              hipStream_t stream) {
  const float* input = (const float*)d_in[0];
  const int* adj     = (const int*)d_in[1];
  const float* W     = (const float*)d_in[2];
  const float* a     = (const float*)d_in[3];
  float* out = (float*)d_out;

  __hip_bfloat16* hT = (__hip_bfloat16*)d_ws;                          // 1 MB
  float* f1p = (float*)((char*)d_ws + (size_t)ODIM * GN * sizeof(__hip_bfloat16));
  float* f2p = f1p + 2 * GN;                                           // 64 KB each

  gat_k1<<<256, 256, 0, stream>>>(input, W, a, hT, f1p, f2p);
  gat_k2<<<256, 256, 0, stream>>>(adj, hT, f1p, f2p, out);
}

// Round 2
// 447.186 us; speedup vs baseline: 1.1724x; 1.1724x over previous
//
#include <hip/hip_runtime.h>
#include <hip/hip_bf16.h>

#define GN 8192
#define KD 256
#define OD 64
#define LOG2E 1.44269504f
#define INV_LOG2E 0.69314718f

typedef __attribute__((ext_vector_type(8))) short bf16x8;
typedef __attribute__((ext_vector_type(4))) float f32x4;

__device__ __forceinline__ short f2bf(float x) {
  __hip_bfloat16 b = __float2bfloat16(x);
  return *reinterpret_cast<short*>(&b);
}

// ---------------------------------------------------------------------------
// Kernel 1: h = input @ W (fp32), 256 blocks x 256 threads, 32 rows/block.
// W staged fully in LDS (no per-k global loads). Emits:
//   hT  [OD][GN] bf16 (transposed, for k2 B-fragments)
//   f1p/f2p fp32, PRE-SCALED by log2(e) so k2 can use exp2 directly
//   the 3 scalar e-outputs (from block 0, which owns rows 0..31)
// ---------------------------------------------------------------------------
__global__ __launch_bounds__(256) void gat_k1(
    const float* __restrict__ input, const float* __restrict__ W,
    const float* __restrict__ a, __hip_bfloat16* __restrict__ hT,
    float* __restrict__ f1p, float* __restrict__ f2p, float* __restrict__ out)
{
  __shared__ float Wl[KD * OD];        // 64 KB, [k][c], c fast
  __shared__ float inT[KD * 33];       // 33.8 KB, [k][r], r fast (pad 33)
  __shared__ float red1[8][32];
  __shared__ float red2[8][32];
  __shared__ float s1row[32];
  __shared__ float s2row[32];

  const int tid = threadIdx.x;
  const int i0 = blockIdx.x * 32;

  // stage W (row-major [256][64] -> direct float4 copy)
  for (int idx = tid; idx < KD * OD / 4; idx += 256)
    ((float4*)Wl)[idx] = ((const float4*)W)[idx];

  // stage input tile [32 rows][256 k] transposed -> inT[k][r]
#pragma unroll
  for (int it = 0; it < 8; ++it) {
    int idx = tid + it * 256;
    int r = idx >> 6, k4 = idx & 63;
    float4 v = *(const float4*)(input + (long)(i0 + r) * KD + k4 * 4);
    inT[(k4 * 4 + 0) * 33 + r] = v.x;
    inT[(k4 * 4 + 1) * 33 + r] = v.y;
    inT[(k4 * 4 + 2) * 33 + r] = v.z;
    inT[(k4 * 4 + 3) * 33 + r] = v.w;
  }
  __syncthreads();

  const int r = tid & 31;      // row within tile
  const int cg = tid >> 5;     // col group: 8 groups x 8 cols
  float acc[8];
#pragma unroll
  for (int c = 0; c < 8; ++c) acc[c] = 0.f;

#pragma unroll 4
  for (int k = 0; k < KD; ++k) {
    float inv = inT[k * 33 + r];
    float4 wa = *(const float4*)&Wl[k * 64 + cg * 8];
    float4 wb = *(const float4*)&Wl[k * 64 + cg * 8 + 4];
    acc[0] += inv * wa.x; acc[1] += inv * wa.y;
    acc[2] += inv * wa.z; acc[3] += inv * wa.w;
    acc[4] += inv * wb.x; acc[5] += inv * wb.y;
    acc[6] += inv * wb.z; acc[7] += inv * wb.w;
  }

  // hT[col][row] bf16
#pragma unroll
  for (int c = 0; c < 8; ++c)
    hT[(long)(cg * 8 + c) * GN + i0 + r] = __float2bfloat16(acc[c]);

  // f1/f2 partials over this thread's 8 cols (unscaled here)
  float s1 = 0.f, s2 = 0.f;
#pragma unroll
  for (int c = 0; c < 8; ++c) {
    s1 += acc[c] * a[cg * 8 + c];
    s2 += acc[c] * a[OD + cg * 8 + c];
  }
  red1[cg][r] = s1; red2[cg][r] = s2;
  __syncthreads();
  if (tid < 32) {
    float f1 = 0.f, f2 = 0.f;
#pragma unroll
    for (int g = 0; g < 8; ++g) { f1 += red1[g][tid]; f2 += red2[g][tid]; }
    s1row[tid] = f1; s2row[tid] = f2;
    f1p[i0 + tid] = f1 * LOG2E;   // pre-scaled for exp2 in k2
    f2p[i0 + tid] = f2 * LOG2E;
  }
  __syncthreads();
  if (blockIdx.x == 0 && tid == 0) {
    float e12 = s1row[1] + s2row[2];
    float e13 = s1row[1] + s2row[3];
    float e32 = s1row[3] + s2row[2];
    out[(long)GN * OD + 0] = fmaxf(e12, 0.01f * e12);
    out[(long)GN * OD + 1] = fmaxf(e13, 0.01f * e13);
    out[(long)GN * OD + 2] = fmaxf(e32, 0.01f * e32);
  }
}

// ---------------------------------------------------------------------------
// Kernel 2: fused mask+softmax(no-max)+alpha@h. BARRIER-FREE main loop.
// 512 blocks x 512 threads (8 waves). Each wave owns a 16-row strip and a
// 1024-wide j slice: adj loaded directly in A-frag layout, w computed in
// registers, MFMA vs B-frags from L2-resident hT. Epilogue combines the
// 8 j-slices in LDS.
// ---------------------------------------------------------------------------
__global__ __launch_bounds__(512, 4) void gat_k2(
    const int* __restrict__ adj, const __hip_bfloat16* __restrict__ hT,
    const float* __restrict__ f1p, const float* __restrict__ f2p,
    float* __restrict__ out)
{
  __shared__ float pbuf[8][16][66];   // 33.8 KB, padded stride 66
  __shared__ float sbuf[8][16];

  const int tid = threadIdx.x;
  const int lane = tid & 63;
  const int wv = tid >> 6;           // j-slice index 0..7
  const int tn = lane & 15;          // A row (m) / B col (n)
  const int quad = lane >> 4;        // k-subrange selector
  const int i0 = blockIdx.x * 16;
  const int jbase = wv * 1024;

  const float f1r = f1p[i0 + tn];    // this lane's row bias (scaled)

  f32x4 acc[4];
#pragma unroll
  for (int nf = 0; nf < 4; ++nf) acc[nf] = (f32x4){0.f, 0.f, 0.f, 0.f};
  f32x4 accS = (f32x4){0.f, 0.f, 0.f, 0.f};

  bf16x8 ones;  // B-frag with ones in column n==0 -> row-sum via MFMA
  {
    short ov = (tn == 0) ? (short)0x3F80 : (short)0;
#pragma unroll
    for (int i = 0; i < 8; ++i) ones[i] = ov;
  }

  const int* ap = adj + (long)(i0 + tn) * GN + jbase + quad * 8;
  const float* fp = f2p + jbase + quad * 8;
  const __hip_bfloat16* hp = hT + jbase + quad * 8 + tn * (long)GN;

  // register double-buffer for the HBM-latency loads (adj) + f2
  int4 a0 = *(const int4*)ap;
  int4 a1 = *(const int4*)(ap + 4);
  float4 F0 = *(const float4*)fp;
  float4 F1 = *(const float4*)(fp + 4);

  for (int c = 0; c < 32; ++c) {
    int4 ca0 = a0, ca1 = a1;
    float4 cF0 = F0, cF1 = F1;
    if (c + 1 < 32) {
      a0 = *(const int4*)(ap + (c + 1) * 32);
      a1 = *(const int4*)(ap + (c + 1) * 32 + 4);
      F0 = *(const float4*)(fp + (c + 1) * 32);
      F1 = *(const float4*)(fp + (c + 1) * 32 + 4);
    }
    // B-frags for current chunk (L2-resident hT)
    bf16x8 b0 = *(const bf16x8*)(hp + c * 32 + 0 * 16 * (long)GN);
    bf16x8 b1 = *(const bf16x8*)(hp + c * 32 + 1 * 16 * (long)GN);
    bf16x8 b2 = *(const bf16x8*)(hp + c * 32 + 2 * 16 * (long)GN);
    bf16x8 b3 = *(const bf16x8*)(hp + c * 32 + 3 * 16 * (long)GN);

    // w = [adj>0] * exp2(lrelu(f1s+f2s))  (inputs pre-scaled by log2 e)
    union { bf16x8 v; short s[8]; } wf;
    {
      float e0 = f1r + cF0.x, e1 = f1r + cF0.y, e2 = f1r + cF0.z, e3 = f1r + cF0.w;
      float e4 = f1r + cF1.x, e5 = f1r + cF1.y, e6 = f1r + cF1.z, e7 = f1r + cF1.w;
      float w0 = (ca0.x > 0) ? exp2f(fmaxf(e0, 0.01f * e0)) : 0.f;
      float w1 = (ca0.y > 0) ? exp2f(fmaxf(e1, 0.01f * e1)) : 0.f;
      float w2 = (ca0.z > 0) ? exp2f(fmaxf(e2, 0.01f * e2)) : 0.f;
      float w3 = (ca0.w > 0) ? exp2f(fmaxf(e3, 0.01f * e3)) : 0.f;
      float w4 = (ca1.x > 0) ? exp2f(fmaxf(e4, 0.01f * e4)) : 0.f;
      float w5 = (ca1.y > 0) ? exp2f(fmaxf(e5, 0.01f * e5)) : 0.f;
      float w6 = (ca1.z > 0) ? exp2f(fmaxf(e6, 0.01f * e6)) : 0.f;
      float w7 = (ca1.w > 0) ? exp2f(fmaxf(e7, 0.01f * e7)) : 0.f;
      wf.s[0] = f2bf(w0); wf.s[1] = f2bf(w1); wf.s[2] = f2bf(w2); wf.s[3] = f2bf(w3);
      wf.s[4] = f2bf(w4); wf.s[5] = f2bf(w5); wf.s[6] = f2bf(w6); wf.s[7] = f2bf(w7);
    }

    acc[0] = __builtin_amdgcn_mfma_f32_16x16x32_bf16(wf.v, b0, acc[0], 0, 0, 0);
    acc[1] = __builtin_amdgcn_mfma_f32_16x16x32_bf16(wf.v, b1, acc[1], 0, 0, 0);
    acc[2] = __builtin_amdgcn_mfma_f32_16x16x32_bf16(wf.v, b2, acc[2], 0, 0, 0);
    acc[3] = __builtin_amdgcn_mfma_f32_16x16x32_bf16(wf.v, b3, acc[3], 0, 0, 0);
    accS   = __builtin_amdgcn_mfma_f32_16x16x32_bf16(wf.v, ones, accS, 0, 0, 0);
  }

  // epilogue: combine 8 j-slices, divide, store
#pragma unroll
  for (int nf = 0; nf < 4; ++nf)
#pragma unroll
    for (int rg = 0; rg < 4; ++rg)
      pbuf[wv][quad * 4 + rg][nf * 16 + tn] = acc[nf][rg];
  if (tn == 0) {
#pragma unroll
    for (int rg = 0; rg < 4; ++rg)
      sbuf[wv][quad * 4 + rg] = accS[rg];
  }
  __syncthreads();
  for (int t = tid; t < 16 * OD; t += 512) {
    int rr = t >> 6, cc = t & 63;
    float num = 0.f, den = 0.f;
#pragma unroll
    for (int w = 0; w < 8; ++w) { num += pbuf[w][rr][cc]; den += sbuf[w][rr]; }
    out[(long)(i0 + rr) * OD + cc] = num / den;
  }
}

extern "C" void kernel_launch(void* const* d_in, const int* in_sizes, int n_in,
                              void* d_out, int out_size, void* d_ws, size_t ws_size,
                              hipStream_t stream) {
  const float* input = (const float*)d_in[0];
  const int* adj     = (const int*)d_in[1];
  const float* W     = (const float*)d_in[2];
  const float* a     = (const float*)d_in[3];
  float* out = (float*)d_out;

  __hip_bfloat16* hT = (__hip_bfloat16*)d_ws;                          // 1 MB
  float* f1p = (float*)((char*)d_ws + (size_t)OD * GN * sizeof(__hip_bfloat16));
  float* f2p = f1p + GN;

  gat_k1<<<256, 256, 0, stream>>>(input, W, a, hT, f1p, f2p, out);
  gat_k2<<<512, 512, 0, stream>>>(adj, hT, f1p, f2p, out);
}

// Round 3
// 433.123 us; speedup vs baseline: 1.2104x; 1.0325x over previous
//
#include <hip/hip_runtime.h>
#include <hip/hip_bf16.h>

#define GN 8192
#define KD 256
#define OD 64
#define LOG2E 1.44269504f

typedef __attribute__((ext_vector_type(8))) short bf16x8;
typedef __attribute__((ext_vector_type(4))) float f32x4;

__device__ __forceinline__ float fexp2(float x) {
#if __has_builtin(__builtin_amdgcn_exp2f)
  return __builtin_amdgcn_exp2f(x);
#else
  return exp2f(x);
#endif
}

// ---------------------------------------------------------------------------
// Kernel 1: h = input @ W (fp32). Emits hT (bf16 [OD][GN]), f1p/f2p fp32
// pre-scaled by log2(e), and the 3 scalar e-outputs.
// ---------------------------------------------------------------------------
__global__ __launch_bounds__(256) void gat_k1(
    const float* __restrict__ input, const float* __restrict__ W,
    const float* __restrict__ a, __hip_bfloat16* __restrict__ hT,
    float* __restrict__ f1p, float* __restrict__ f2p, float* __restrict__ out)
{
  __shared__ float Wl[KD * OD];        // 64 KB, [k][c]
  __shared__ float inT[KD * 33];       // [k][r], pad 33
  __shared__ float red1[8][32];
  __shared__ float red2[8][32];
  __shared__ float s1row[32];
  __shared__ float s2row[32];

  const int tid = threadIdx.x;
  const int i0 = blockIdx.x * 32;

  for (int idx = tid; idx < KD * OD / 4; idx += 256)
    ((float4*)Wl)[idx] = ((const float4*)W)[idx];

#pragma unroll
  for (int it = 0; it < 8; ++it) {
    int idx = tid + it * 256;
    int r = idx >> 6, k4 = idx & 63;
    float4 v = *(const float4*)(input + (long)(i0 + r) * KD + k4 * 4);
    inT[(k4 * 4 + 0) * 33 + r] = v.x;
    inT[(k4 * 4 + 1) * 33 + r] = v.y;
    inT[(k4 * 4 + 2) * 33 + r] = v.z;
    inT[(k4 * 4 + 3) * 33 + r] = v.w;
  }
  __syncthreads();

  const int r = tid & 31;
  const int cg = tid >> 5;
  float acc[8];
#pragma unroll
  for (int c = 0; c < 8; ++c) acc[c] = 0.f;

#pragma unroll 4
  for (int k = 0; k < KD; ++k) {
    float inv = inT[k * 33 + r];
    float4 wa = *(const float4*)&Wl[k * 64 + cg * 8];
    float4 wb = *(const float4*)&Wl[k * 64 + cg * 8 + 4];
    acc[0] += inv * wa.x; acc[1] += inv * wa.y;
    acc[2] += inv * wa.z; acc[3] += inv * wa.w;
    acc[4] += inv * wb.x; acc[5] += inv * wb.y;
    acc[6] += inv * wb.z; acc[7] += inv * wb.w;
  }

#pragma unroll
  for (int c = 0; c < 8; ++c)
    hT[(long)(cg * 8 + c) * GN + i0 + r] = __float2bfloat16(acc[c]);

  float s1 = 0.f, s2 = 0.f;
#pragma unroll
  for (int c = 0; c < 8; ++c) {
    s1 += acc[c] * a[cg * 8 + c];
    s2 += acc[c] * a[OD + cg * 8 + c];
  }
  red1[cg][r] = s1; red2[cg][r] = s2;
  __syncthreads();
  if (tid < 32) {
    float f1 = 0.f, f2 = 0.f;
#pragma unroll
    for (int g = 0; g < 8; ++g) { f1 += red1[g][tid]; f2 += red2[g][tid]; }
    s1row[tid] = f1; s2row[tid] = f2;
    f1p[i0 + tid] = f1 * LOG2E;
    f2p[i0 + tid] = f2 * LOG2E;
  }
  __syncthreads();
  if (blockIdx.x == 0 && tid == 0) {
    float e12 = s1row[1] + s2row[2];
    float e13 = s1row[1] + s2row[3];
    float e32 = s1row[3] + s2row[2];
    out[(long)GN * OD + 0] = fmaxf(e12, 0.01f * e12);
    out[(long)GN * OD + 1] = fmaxf(e13, 0.01f * e13);
    out[(long)GN * OD + 2] = fmaxf(e32, 0.01f * e32);
  }
}

// ---------------------------------------------------------------------------
// Kernel 2: fused mask+softmax(no-max)+alpha@h. Barrier-free main loop,
// fully unrolled 32 chunks with immediate-offset loads and 1-chunk-ahead
// register double buffering of ALL streams. Native v_exp_f32; bf16 pack
// via v_perm truncation (num & den share the same quantized w).
// ---------------------------------------------------------------------------
__global__ __launch_bounds__(512, 4) void gat_k2(
    const int* __restrict__ adj, const __hip_bfloat16* __restrict__ hT,
    const float* __restrict__ f1p, const float* __restrict__ f2p,
    float* __restrict__ out)
{
  __shared__ float pbuf[8][16][66];
  __shared__ float sbuf[8][16];

  const int tid = threadIdx.x;
  const int lane = tid & 63;
  const int wv = tid >> 6;           // j-slice 0..7
  const int tn = lane & 15;
  const int quad = lane >> 4;
  const int i0 = blockIdx.x * 16;
  const int jbase = wv * 1024;

  const float f1r = f1p[i0 + tn];

  f32x4 acc[4];
#pragma unroll
  for (int nf = 0; nf < 4; ++nf) acc[nf] = (f32x4){0.f, 0.f, 0.f, 0.f};
  f32x4 accS = (f32x4){0.f, 0.f, 0.f, 0.f};

  bf16x8 ones;  // ones in column n==0 -> row sums via MFMA
  {
    short ov = (tn == 0) ? (short)0x3F80 : (short)0;
#pragma unroll
    for (int i = 0; i < 8; ++i) ones[i] = ov;
  }

  const int* ap = adj + (long)(i0 + tn) * GN + jbase + quad * 8;
  const float* fp = f2p + jbase + quad * 8;
  const __hip_bfloat16* hp = hT + (long)tn * GN + jbase + quad * 8;

  // double-buffered register streams
  int4 A0[2], A1[2];
  float4 F0[2], F1[2];
  bf16x8 B[2][4];

  // prologue: chunk 0 -> slot 0
  A0[0] = *(const int4*)ap;
  A1[0] = *(const int4*)(ap + 4);
  F0[0] = *(const float4*)fp;
  F1[0] = *(const float4*)(fp + 4);
#pragma unroll
  for (int g = 0; g < 4; ++g)
    B[0][g] = *(const bf16x8*)(hp + (long)g * (16 * GN));

#pragma unroll
  for (int c = 0; c < 32; ++c) {
    const int cur = c & 1, nxt = cur ^ 1;
    if (c + 1 < 32) {  // prefetch chunk c+1 (immediate offsets, no addr VALU)
      A0[nxt] = *(const int4*)(ap + (c + 1) * 32);
      A1[nxt] = *(const int4*)(ap + (c + 1) * 32 + 4);
      F0[nxt] = *(const float4*)(fp + (c + 1) * 32);
      F1[nxt] = *(const float4*)(fp + (c + 1) * 32 + 4);
#pragma unroll
      for (int g = 0; g < 4; ++g)
        B[nxt][g] = *(const bf16x8*)(hp + (long)g * (16 * GN) + (c + 1) * 32);
    }

    // w = exp2( adj>0 ? lrelu(f1s+f2s) : -256 ), bf16-truncated
    const int4 ca0 = A0[cur], ca1 = A1[cur];
    const float4 cF0 = F0[cur], cF1 = F1[cur];
    float e0 = f1r + cF0.x, e1 = f1r + cF0.y, e2 = f1r + cF0.z, e3 = f1r + cF0.w;
    float e4 = f1r + cF1.x, e5 = f1r + cF1.y, e6 = f1r + cF1.z, e7 = f1r + cF1.w;
    float m0 = fmaxf(e0, 0.01f * e0), m1 = fmaxf(e1, 0.01f * e1);
    float m2 = fmaxf(e2, 0.01f * e2), m3 = fmaxf(e3, 0.01f * e3);
    float m4 = fmaxf(e4, 0.01f * e4), m5 = fmaxf(e5, 0.01f * e5);
    float m6 = fmaxf(e6, 0.01f * e6), m7 = fmaxf(e7, 0.01f * e7);
    float w0 = fexp2((ca0.x > 0) ? m0 : -256.f);
    float w1 = fexp2((ca0.y > 0) ? m1 : -256.f);
    float w2 = fexp2((ca0.z > 0) ? m2 : -256.f);
    float w3 = fexp2((ca0.w > 0) ? m3 : -256.f);
    float w4 = fexp2((ca1.x > 0) ? m4 : -256.f);
    float w5 = fexp2((ca1.y > 0) ? m5 : -256.f);
    float w6 = fexp2((ca1.z > 0) ? m6 : -256.f);
    float w7 = fexp2((ca1.w > 0) ? m7 : -256.f);

    union { bf16x8 v; unsigned u[4]; } wf;
    wf.u[0] = __builtin_amdgcn_perm(__float_as_uint(w1), __float_as_uint(w0), 0x07060302u);
    wf.u[1] = __builtin_amdgcn_perm(__float_as_uint(w3), __float_as_uint(w2), 0x07060302u);
    wf.u[2] = __builtin_amdgcn_perm(__float_as_uint(w5), __float_as_uint(w4), 0x07060302u);
    wf.u[3] = __builtin_amdgcn_perm(__float_as_uint(w7), __float_as_uint(w6), 0x07060302u);

    acc[0] = __builtin_amdgcn_mfma_f32_16x16x32_bf16(wf.v, B[cur][0], acc[0], 0, 0, 0);
    acc[1] = __builtin_amdgcn_mfma_f32_16x16x32_bf16(wf.v, B[cur][1], acc[1], 0, 0, 0);
    acc[2] = __builtin_amdgcn_mfma_f32_16x16x32_bf16(wf.v, B[cur][2], acc[2], 0, 0, 0);
    acc[3] = __builtin_amdgcn_mfma_f32_16x16x32_bf16(wf.v, B[cur][3], acc[3], 0, 0, 0);
    accS   = __builtin_amdgcn_mfma_f32_16x16x32_bf16(wf.v, ones,      accS,   0, 0, 0);
  }

  // epilogue: combine the 8 j-slices, divide, store
#pragma unroll
  for (int nf = 0; nf < 4; ++nf)
#pragma unroll
    for (int rg = 0; rg < 4; ++rg)
      pbuf[wv][quad * 4 + rg][nf * 16 + tn] = acc[nf][rg];
  if (tn == 0) {
#pragma unroll
    for (int rg = 0; rg < 4; ++rg)
      sbuf[wv][quad * 4 + rg] = accS[rg];
  }
  __syncthreads();
  for (int t = tid; t < 16 * OD; t += 512) {
    int rr = t >> 6, cc = t & 63;
    float num = 0.f, den = 0.f;
#pragma unroll
    for (int w = 0; w < 8; ++w) { num += pbuf[w][rr][cc]; den += sbuf[w][rr]; }
    out[(long)(i0 + rr) * OD + cc] = num / den;
  }
}

extern "C" void kernel_launch(void* const* d_in, const int* in_sizes, int n_in,
                              void* d_out, int out_size, void* d_ws, size_t ws_size,
                              hipStream_t stream) {
  const float* input = (const float*)d_in[0];
  const int* adj     = (const int*)d_in[1];
  const float* W     = (const float*)d_in[2];
  const float* a     = (const float*)d_in[3];
  float* out = (float*)d_out;

  __hip_bfloat16* hT = (__hip_bfloat16*)d_ws;                          // 1 MB
  float* f1p = (float*)((char*)d_ws + (size_t)OD * GN * sizeof(__hip_bfloat16));
  float* f2p = f1p + GN;

  gat_k1<<<256, 256, 0, stream>>>(input, W, a, hT, f1p, f2p, out);
  gat_k2<<<512, 512, 0, stream>>>(adj, hT, f1p, f2p, out);
}

// Round 4
// 392.613 us; speedup vs baseline: 1.3353x; 1.1032x over previous
//
#include <hip/hip_runtime.h>
#include <hip/hip_bf16.h>

#define GN 8192
#define KD 256
#define OD 64
#define LOG2E 1.44269504f
#define ASTR 264   // LDS row stride for staged adj (ints): 16B-aligned, padded

typedef __attribute__((ext_vector_type(8))) short bf16x8;
typedef __attribute__((ext_vector_type(4))) float f32x4;

__device__ __forceinline__ float fexp2(float x) {
#if __has_builtin(__builtin_amdgcn_exp2f)
  return __builtin_amdgcn_exp2f(x);
#else
  return exp2f(x);
#endif
}

// ---------------------------------------------------------------------------
// Kernel 1: h = input @ W (fp32). Emits hT (bf16 [OD][GN]), f1p/f2p fp32
// pre-scaled by log2(e), and the 3 scalar e-outputs.
// ---------------------------------------------------------------------------
__global__ __launch_bounds__(256) void gat_k1(
    const float* __restrict__ input, const float* __restrict__ W,
    const float* __restrict__ a, __hip_bfloat16* __restrict__ hT,
    float* __restrict__ f1p, float* __restrict__ f2p, float* __restrict__ out)
{
  __shared__ float Wl[KD * OD];        // 64 KB, [k][c]
  __shared__ float inT[KD * 33];       // [k][r], pad 33
  __shared__ float red1[8][32];
  __shared__ float red2[8][32];
  __shared__ float s1row[32];
  __shared__ float s2row[32];

  const int tid = threadIdx.x;
  const int i0 = blockIdx.x * 32;

  for (int idx = tid; idx < KD * OD / 4; idx += 256)
    ((float4*)Wl)[idx] = ((const float4*)W)[idx];

#pragma unroll
  for (int it = 0; it < 8; ++it) {
    int idx = tid + it * 256;
    int r = idx >> 6, k4 = idx & 63;
    float4 v = *(const float4*)(input + (long)(i0 + r) * KD + k4 * 4);
    inT[(k4 * 4 + 0) * 33 + r] = v.x;
    inT[(k4 * 4 + 1) * 33 + r] = v.y;
    inT[(k4 * 4 + 2) * 33 + r] = v.z;
    inT[(k4 * 4 + 3) * 33 + r] = v.w;
  }
  __syncthreads();

  const int r = tid & 31;
  const int cg = tid >> 5;
  float acc[8];
#pragma unroll
  for (int c = 0; c < 8; ++c) acc[c] = 0.f;

#pragma unroll 4
  for (int k = 0; k < KD; ++k) {
    float inv = inT[k * 33 + r];
    float4 wa = *(const float4*)&Wl[k * 64 + cg * 8];
    float4 wb = *(const float4*)&Wl[k * 64 + cg * 8 + 4];
    acc[0] += inv * wa.x; acc[1] += inv * wa.y;
    acc[2] += inv * wa.z; acc[3] += inv * wa.w;
    acc[4] += inv * wb.x; acc[5] += inv * wb.y;
    acc[6] += inv * wb.z; acc[7] += inv * wb.w;
  }

#pragma unroll
  for (int c = 0; c < 8; ++c)
    hT[(long)(cg * 8 + c) * GN + i0 + r] = __float2bfloat16(acc[c]);

  float s1 = 0.f, s2 = 0.f;
#pragma unroll
  for (int c = 0; c < 8; ++c) {
    s1 += acc[c] * a[cg * 8 + c];
    s2 += acc[c] * a[OD + cg * 8 + c];
  }
  red1[cg][r] = s1; red2[cg][r] = s2;
  __syncthreads();
  if (tid < 32) {
    float f1 = 0.f, f2 = 0.f;
#pragma unroll
    for (int g = 0; g < 8; ++g) { f1 += red1[g][tid]; f2 += red2[g][tid]; }
    s1row[tid] = f1; s2row[tid] = f2;
    f1p[i0 + tid] = f1 * LOG2E;
    f2p[i0 + tid] = f2 * LOG2E;
  }
  __syncthreads();
  if (blockIdx.x == 0 && tid == 0) {
    float e12 = s1row[1] + s2row[2];
    float e13 = s1row[1] + s2row[3];
    float e32 = s1row[3] + s2row[2];
    out[(long)GN * OD + 0] = fmaxf(e12, 0.01f * e12);
    out[(long)GN * OD + 1] = fmaxf(e13, 0.01f * e13);
    out[(long)GN * OD + 2] = fmaxf(e32, 0.01f * e32);
  }
}

// ---------------------------------------------------------------------------
// Kernel 2: fused mask+softmax(no-max)+alpha@h.
// m93-style double-buffered LDS staging of adj: VGPR load -> ds_write ->
// barrier -> ds_read -> w-gen -> MFMA. The barrier pipeline is compiler-proof
// (loads of chunk c+1 issue before compute of chunk c; ds_write consumes them
// after compute). 512 blocks x 256 threads; block = 16 rows x all 8192 j in
// 32 chunks of 256 j; the 4 waves partition K (2 MFMA k-steps each);
// epilogue reduces wave partials in LDS.
// ---------------------------------------------------------------------------
__global__ __launch_bounds__(256, 2) void gat_k2(
    const int* __restrict__ adj, const __hip_bfloat16* __restrict__ hT,
    const float* __restrict__ f1p, const float* __restrict__ f2p,
    float* __restrict__ out)
{
  __shared__ int abuf[2][16 * ASTR];   // 33 KB staged adj, padded stride
  __shared__ float pb[4][16][68];      // 17.4 KB wave-partial numerators
  __shared__ float sb[4][16];          // wave-partial denominators

  const int tid = threadIdx.x;
  const int lane = tid & 63;
  const int wv = tid >> 6;             // wave 0..3 -> k-steps {2wv, 2wv+1}
  const int tn = lane & 15;            // MFMA m/n index
  const int quad = lane >> 4;          // MFMA k-quad
  const int i0 = blockIdx.x * 16;

  // staging assignment: thread -> row sr, 16B column segment sc (x4 per chunk)
  const int sr = tid >> 4;             // 0..15
  const int sc = (tid & 15) * 4;       // int offset 0..60
  const int* gsrc = adj + (long)(i0 + sr) * GN + sc;

  const float f1r = f1p[i0 + tn];

  // per-wave k-step j-offsets within a 256-j chunk
  const int jo0 = (2 * wv) * 32 + quad * 8;
  const int jo1 = (2 * wv + 1) * 32 + quad * 8;
  const __hip_bfloat16* hbase = hT + (long)tn * GN;

  f32x4 acc[4];
#pragma unroll
  for (int nf = 0; nf < 4; ++nf) acc[nf] = (f32x4){0.f, 0.f, 0.f, 0.f};
  f32x4 accS = (f32x4){0.f, 0.f, 0.f, 0.f};

  bf16x8 ones;  // ones in column n==0 -> row sums via MFMA
  {
    short ov = (tn == 0) ? (short)0x3F80 : (short)0;
#pragma unroll
    for (int i = 0; i < 8; ++i) ones[i] = ov;
  }

  int4 st[4];
  // prologue: stage chunk 0
#pragma unroll
  for (int k = 0; k < 4; ++k) st[k] = *(const int4*)(gsrc + 64 * k);
#pragma unroll
  for (int k = 0; k < 4; ++k) *(int4*)&abuf[0][sr * ASTR + sc + 64 * k] = st[k];
  __syncthreads();

  for (int c = 0; c < 32; ++c) {
    const int cur = c & 1, nxt = cur ^ 1;
    if (c < 31) {  // issue next chunk's global loads (latency hidden by compute)
#pragma unroll
      for (int k = 0; k < 4; ++k)
        st[k] = *(const int4*)(gsrc + (c + 1) * 256 + 64 * k);
    }

    // ---- compute chunk c from LDS ----
    const int4 a0 = *(const int4*)&abuf[cur][tn * ASTR + jo0];
    const int4 a1 = *(const int4*)&abuf[cur][tn * ASTR + jo0 + 4];
    const int4 a2 = *(const int4*)&abuf[cur][tn * ASTR + jo1];
    const int4 a3 = *(const int4*)&abuf[cur][tn * ASTR + jo1 + 4];
    const float4 f20 = *(const float4*)(f2p + c * 256 + jo0);
    const float4 f21 = *(const float4*)(f2p + c * 256 + jo0 + 4);
    const float4 f22 = *(const float4*)(f2p + c * 256 + jo1);
    const float4 f23 = *(const float4*)(f2p + c * 256 + jo1 + 4);
    bf16x8 B0[4], B1[4];
#pragma unroll
    for (int nf = 0; nf < 4; ++nf) {
      B0[nf] = *(const bf16x8*)(hbase + (long)nf * (16 * GN) + c * 256 + jo0);
      B1[nf] = *(const bf16x8*)(hbase + (long)nf * (16 * GN) + c * 256 + jo1);
    }

    union { bf16x8 v; unsigned u[4]; } w0, w1;
    {
      float e0 = f1r + f20.x, e1 = f1r + f20.y, e2 = f1r + f20.z, e3 = f1r + f20.w;
      float e4 = f1r + f21.x, e5 = f1r + f21.y, e6 = f1r + f21.z, e7 = f1r + f21.w;
      float v0 = fexp2((a0.x > 0) ? fmaxf(e0, 0.01f * e0) : -256.f);
      float v1 = fexp2((a0.y > 0) ? fmaxf(e1, 0.01f * e1) : -256.f);
      float v2 = fexp2((a0.z > 0) ? fmaxf(e2, 0.01f * e2) : -256.f);
      float v3 = fexp2((a0.w > 0) ? fmaxf(e3, 0.01f * e3) : -256.f);
      float v4 = fexp2((a1.x > 0) ? fmaxf(e4, 0.01f * e4) : -256.f);
      float v5 = fexp2((a1.y > 0) ? fmaxf(e5, 0.01f * e5) : -256.f);
      float v6 = fexp2((a1.z > 0) ? fmaxf(e6, 0.01f * e6) : -256.f);
      float v7 = fexp2((a1.w > 0) ? fmaxf(e7, 0.01f * e7) : -256.f);
      w0.u[0] = __builtin_amdgcn_perm(__float_as_uint(v1), __float_as_uint(v0), 0x07060302u);
      w0.u[1] = __builtin_amdgcn_perm(__float_as_uint(v3), __float_as_uint(v2), 0x07060302u);
      w0.u[2] = __builtin_amdgcn_perm(__float_as_uint(v5), __float_as_uint(v4), 0x07060302u);
      w0.u[3] = __builtin_amdgcn_perm(__float_as_uint(v7), __float_as_uint(v6), 0x07060302u);
    }
    {
      float e0 = f1r + f22.x, e1 = f1r + f22.y, e2 = f1r + f22.z, e3 = f1r + f22.w;
      float e4 = f1r + f23.x, e5 = f1r + f23.y, e6 = f1r + f23.z, e7 = f1r + f23.w;
      float v0 = fexp2((a2.x > 0) ? fmaxf(e0, 0.01f * e0) : -256.f);
      float v1 = fexp2((a2.y > 0) ? fmaxf(e1, 0.01f * e1) : -256.f);
      float v2 = fexp2((a2.z > 0) ? fmaxf(e2, 0.01f * e2) : -256.f);
      float v3 = fexp2((a2.w > 0) ? fmaxf(e3, 0.01f * e3) : -256.f);
      float v4 = fexp2((a3.x > 0) ? fmaxf(e4, 0.01f * e4) : -256.f);
      float v5 = fexp2((a3.y > 0) ? fmaxf(e5, 0.01f * e5) : -256.f);
      float v6 = fexp2((a3.z > 0) ? fmaxf(e6, 0.01f * e6) : -256.f);
      float v7 = fexp2((a3.w > 0) ? fmaxf(e7, 0.01f * e7) : -256.f);
      w1.u[0] = __builtin_amdgcn_perm(__float_as_uint(v1), __float_as_uint(v0), 0x07060302u);
      w1.u[1] = __builtin_amdgcn_perm(__float_as_uint(v3), __float_as_uint(v2), 0x07060302u);
      w1.u[2] = __builtin_amdgcn_perm(__float_as_uint(v5), __float_as_uint(v4), 0x07060302u);
      w1.u[3] = __builtin_amdgcn_perm(__float_as_uint(v7), __float_as_uint(v6), 0x07060302u);
    }

#pragma unroll
    for (int nf = 0; nf < 4; ++nf)
      acc[nf] = __builtin_amdgcn_mfma_f32_16x16x32_bf16(w0.v, B0[nf], acc[nf], 0, 0, 0);
    accS = __builtin_amdgcn_mfma_f32_16x16x32_bf16(w0.v, ones, accS, 0, 0, 0);
#pragma unroll
    for (int nf = 0; nf < 4; ++nf)
      acc[nf] = __builtin_amdgcn_mfma_f32_16x16x32_bf16(w1.v, B1[nf], acc[nf], 0, 0, 0);
    accS = __builtin_amdgcn_mfma_f32_16x16x32_bf16(w1.v, ones, accS, 0, 0, 0);

    if (c < 31) {  // commit staged chunk c+1 (s_waitcnt on st auto-inserted here)
#pragma unroll
      for (int k = 0; k < 4; ++k)
        *(int4*)&abuf[nxt][sr * ASTR + sc + 64 * k] = st[k];
    }
    __syncthreads();
  }

  // epilogue: reduce the 4 wave K-partials, divide, store
#pragma unroll
  for (int nf = 0; nf < 4; ++nf)
#pragma unroll
    for (int rg = 0; rg < 4; ++rg)
      pb[wv][quad * 4 + rg][nf * 16 + tn] = acc[nf][rg];
  if (tn == 0) {
#pragma unroll
    for (int rg = 0; rg < 4; ++rg)
      sb[wv][quad * 4 + rg] = accS[rg];
  }
  __syncthreads();
  for (int t = tid; t < 16 * OD; t += 256) {
    int rr = t >> 6, cc = t & 63;
    float num = pb[0][rr][cc] + pb[1][rr][cc] + pb[2][rr][cc] + pb[3][rr][cc];
    float den = sb[0][rr] + sb[1][rr] + sb[2][rr] + sb[3][rr];
    out[(long)(i0 + rr) * OD + cc] = num / den;
  }
}

extern "C" void kernel_launch(void* const* d_in, const int* in_sizes, int n_in,
                              void* d_out, int out_size, void* d_ws, size_t ws_size,
                              hipStream_t stream) {
  const float* input = (const float*)d_in[0];
  const int* adj     = (const int*)d_in[1];
  const float* W     = (const float*)d_in[2];
  const float* a     = (const float*)d_in[3];
  float* out = (float*)d_out;

  __hip_bfloat16* hT = (__hip_bfloat16*)d_ws;                          // 1 MB
  float* f1p = (float*)((char*)d_ws + (size_t)OD * GN * sizeof(__hip_bfloat16));
  float* f2p = f1p + GN;

  gat_k1<<<256, 256, 0, stream>>>(input, W, a, hT, f1p, f2p, out);
  gat_k2<<<512, 256, 0, stream>>>(adj, hT, f1p, f2p, out);
}